// Round 1
// baseline (484.477 us; speedup 1.0000x reference)
//
#include <hip/hip_runtime.h>
#include <hip/hip_bf16.h>
#include <stdint.h>

#define B_    4
#define N_    8192
#define K_    32
#define CX_   67      // 3 + C_IN
#define CMID_ 64
#define COUT_ 128

#define XSTR  104     // LDS K-stride for X / W1 rows: >=96, mult of 8
#define HSTR  72      // LDS stride for H1 / W2 rows: >=64, mult of 8

#define NWG   2048
#define TPG   4       // tiles per WG; tile = 4 n-values (one per wave)

typedef __bf16 bf16_t;
typedef bf16_t bf16x8 __attribute__((ext_vector_type(8)));
typedef bf16_t bf16x4 __attribute__((ext_vector_type(4)));
typedef float  f32x4  __attribute__((ext_vector_type(4)));

__global__ __launch_bounds__(256, 3)
void sa_kernel(const float* __restrict__ dp, const float* __restrict__ fj,
               const float* __restrict__ W1, const float* __restrict__ b1,
               const float* __restrict__ W2, const float* __restrict__ b2,
               float* __restrict__ out)
{
    __shared__ bf16_t W1s[64 * XSTR];        // [o][k] row-major, k zero-padded to 96+
    __shared__ bf16_t W2s[COUT_ * HSTR];     // [o][k] row-major
    __shared__ bf16_t Xs[4][16 * XSTR];      // per-wave [col][chan]
    __shared__ bf16_t H1s[4][16 * HSTR];     // per-wave [col][row]

    const int tid  = threadIdx.x;
    const int wave = tid >> 6;
    const int lane = tid & 63;
    const int lrow = lane & 15;   // A-row / B-col / D-col within 16-tile
    const int g    = lane >> 4;   // 16-lane group
    const int lk   = g * 8;       // fragment k-base

    // ---- one-time: stage weights (bf16, zero-padded), zero X pad region ----
    for (int i = tid; i < 64 * XSTR; i += 256) {
        int o = i / XSTR, c = i - o * XSTR;
        W1s[i] = (c < CX_) ? (bf16_t)W1[o * CX_ + c] : (bf16_t)0.f;
    }
    for (int i = tid; i < COUT_ * HSTR; i += 256) {
        int o = i / HSTR, c = i - o * HSTR;
        W2s[i] = (c < CMID_) ? (bf16_t)W2[o * CMID_ + c] : (bf16_t)0.f;
    }
    for (int i = tid; i < 4 * 16 * XSTR; i += 256)
        (&Xs[0][0])[i] = (bf16_t)0.f;
    __syncthreads();

    const int r = lane >> 2;   // staging: channel sub-row 0..15
    const int q = lane & 3;    // staging: float4 slot (covers 4 cols)

    #pragma unroll 1
    for (int t = 0; t < TPG; ++t) {
        const int T = blockIdx.x * TPG + t;       // 0..8191
        const int b = T >> 11;                    // / 2048
        const int n = ((T & 2047) << 2) + wave;   // this wave's point

        float macc[32];                           // pooled max, [ot][r2]
        #pragma unroll
        for (int i = 0; i < 32; ++i) macc[i] = 0.f;   // relu => 0 is identity

        #pragma unroll 1
        for (int h = 0; h < 2; ++h) {             // two 16-col halves of the k-group
            // ---- stage X: cols = k in [h*16, h*16+16), channels 0..66 (+zeros to 79) ----
            {
                const size_t plane = (size_t)N_ * K_;
                const size_t roff  = (size_t)n * K_ + h * 16 + q * 4;
                const float* dpb = dp + (size_t)b * 3  * plane + roff;
                const float* fjb = fj + (size_t)b * 64 * plane + roff;
                bf16_t* xp = Xs[wave];
                #pragma unroll
                for (int c0 = 0; c0 < 80; c0 += 16) {
                    int c = c0 + r;
                    float4 v = make_float4(0.f, 0.f, 0.f, 0.f);
                    if (c < CX_) {
                        const float* p = (c < 3) ? dpb + (size_t)c * plane
                                                 : fjb + (size_t)(c - 3) * plane;
                        v = *(const float4*)p;
                    }
                    const int cb = q * 4;
                    xp[(cb + 0) * XSTR + c] = (bf16_t)v.x;
                    xp[(cb + 1) * XSTR + c] = (bf16_t)v.y;
                    xp[(cb + 2) * XSTR + c] = (bf16_t)v.z;
                    xp[(cb + 3) * XSTR + c] = (bf16_t)v.w;
                }
            }

            // ---- layer 1: acc1 = W1 * X (K = 96 padded, 3 chunks) ----
            f32x4 acc1[4] = {};
            #pragma unroll
            for (int kc = 0; kc < 3; ++kc) {
                bf16x8 bfrag = *(const bf16x8*)&Xs[wave][lrow * XSTR + kc * 32 + lk];
                #pragma unroll
                for (int rt = 0; rt < 4; ++rt) {
                    bf16x8 afrag = *(const bf16x8*)&W1s[(rt * 16 + lrow) * XSTR + kc * 32 + lk];
                    acc1[rt] = __builtin_amdgcn_mfma_f32_16x16x32_bf16(afrag, bfrag, acc1[rt], 0, 0, 0);
                }
            }
            // epilogue 1: bias + relu -> bf16 -> H1s[col][row]
            #pragma unroll
            for (int rt = 0; rt < 4; ++rt) {
                float4 bb = *(const float4*)(b1 + rt * 16 + g * 4);
                bf16x4 tv;
                tv[0] = (bf16_t)fmaxf(acc1[rt][0] + bb.x, 0.f);
                tv[1] = (bf16_t)fmaxf(acc1[rt][1] + bb.y, 0.f);
                tv[2] = (bf16_t)fmaxf(acc1[rt][2] + bb.z, 0.f);
                tv[3] = (bf16_t)fmaxf(acc1[rt][3] + bb.w, 0.f);
                *(bf16x4*)&H1s[wave][lrow * HSTR + rt * 16 + g * 4] = tv;
            }

            // ---- layer 2: acc2 = W2 * H1 (K = 64, 2 chunks) ----
            f32x4 acc2[8] = {};
            #pragma unroll
            for (int kc = 0; kc < 2; ++kc) {
                bf16x8 bfrag = *(const bf16x8*)&H1s[wave][lrow * HSTR + kc * 32 + lk];
                #pragma unroll
                for (int ot = 0; ot < 8; ++ot) {
                    bf16x8 afrag = *(const bf16x8*)&W2s[(ot * 16 + lrow) * HSTR + kc * 32 + lk];
                    acc2[ot] = __builtin_amdgcn_mfma_f32_16x16x32_bf16(afrag, bfrag, acc2[ot], 0, 0, 0);
                }
            }
            // epilogue 2: bias, fold max (relu absorbed: macc >= 0)
            #pragma unroll
            for (int ot = 0; ot < 8; ++ot) {
                float4 bb = *(const float4*)(b2 + ot * 16 + g * 4);
                macc[ot*4+0] = fmaxf(macc[ot*4+0], acc2[ot][0] + bb.x);
                macc[ot*4+1] = fmaxf(macc[ot*4+1], acc2[ot][1] + bb.y);
                macc[ot*4+2] = fmaxf(macc[ot*4+2], acc2[ot][2] + bb.z);
                macc[ot*4+3] = fmaxf(macc[ot*4+3], acc2[ot][3] + bb.w);
            }
        }

        // ---- pool across the 16 column-lanes (butterfly over lrow bits) ----
        #pragma unroll
        for (int i = 0; i < 32; ++i) {
            float v = macc[i];
            v = fmaxf(v, __shfl_xor(v, 1, 64));
            v = fmaxf(v, __shfl_xor(v, 2, 64));
            v = fmaxf(v, __shfl_xor(v, 4, 64));
            v = fmaxf(v, __shfl_xor(v, 8, 64));
            macc[i] = v;
        }
        if (lrow == 0) {
            const size_t obase = (size_t)b * COUT_ * N_ + n;
            #pragma unroll
            for (int ot = 0; ot < 8; ++ot) {
                #pragma unroll
                for (int r2 = 0; r2 < 4; ++r2)
                    out[obase + (size_t)(ot * 16 + g * 4 + r2) * N_] = macc[ot * 4 + r2];
            }
        }
    }
}

extern "C" void kernel_launch(void* const* d_in, const int* in_sizes, int n_in,
                              void* d_out, int out_size, void* d_ws, size_t ws_size,
                              hipStream_t stream) {
    // inputs: 0=p (unused), 1=f (unused), 2=dp, 3=fj, 4=W1, 5=b1, 6=W2, 7=b2
    const float* dp = (const float*)d_in[2];
    const float* fj = (const float*)d_in[3];
    const float* W1 = (const float*)d_in[4];
    const float* b1 = (const float*)d_in[5];
    const float* W2 = (const float*)d_in[6];
    const float* b2 = (const float*)d_in[7];
    float* out = (float*)d_out;
    hipLaunchKernelGGL(sa_kernel, dim3(NWG), dim3(256), 0, stream,
                       dp, fj, W1, b1, W2, b2, out);
}

// Round 2
// 171.587 us; speedup vs baseline: 2.8235x; 2.8235x over previous
//
#include <hip/hip_runtime.h>
#include <hip/hip_bf16.h>
#include <stdint.h>

#define B_    4
#define N_    8192
#define K_    32
#define CX    67      // 3 + C_IN
#define CMID  64
#define COUT  128

#define CSTR  100     // Xs chan stride (>=96 for kc=2 full chunk, mult of 4, bank-friendly)
#define HSTR  72      // Hbuf chan stride (mult of 8 for b128-aligned reads)
#define TPG   4       // n-groups per WG (each group = 4 n, one per wave)

typedef __bf16 bf16_t;
typedef bf16_t bf16x8 __attribute__((ext_vector_type(8)));
typedef bf16_t bf16x4 __attribute__((ext_vector_type(4)));
typedef float  f32x4  __attribute__((ext_vector_type(4)));

__device__ __forceinline__ uint32_t pack2bf(float a, float b) {
    union { bf16_t h[2]; uint32_t u; } x;
    x.h[0] = (bf16_t)a; x.h[1] = (bf16_t)b;
    return x.u;
}

__device__ __forceinline__ float dpp_max16(float x) {
    // max-reduce over each 16-lane row (all lanes end with the max)
    int i;
    i = __builtin_amdgcn_update_dpp(__builtin_bit_cast(int, x), __builtin_bit_cast(int, x), 0xB1, 0xf, 0xf, false);  // quad xor1
    x = fmaxf(x, __builtin_bit_cast(float, i));
    i = __builtin_amdgcn_update_dpp(__builtin_bit_cast(int, x), __builtin_bit_cast(int, x), 0x4E, 0xf, 0xf, false);  // quad xor2
    x = fmaxf(x, __builtin_bit_cast(float, i));
    i = __builtin_amdgcn_update_dpp(__builtin_bit_cast(int, x), __builtin_bit_cast(int, x), 0x141, 0xf, 0xf, false); // half mirror
    x = fmaxf(x, __builtin_bit_cast(float, i));
    i = __builtin_amdgcn_update_dpp(__builtin_bit_cast(int, x), __builtin_bit_cast(int, x), 0x128, 0xf, 0xf, false); // row ror:8
    x = fmaxf(x, __builtin_bit_cast(float, i));
    return x;
}

template<bool DIRECT>
__global__ __launch_bounds__(256, 2)
void sa_main(const float* __restrict__ dp, const float* __restrict__ fj,
             const float* __restrict__ W1, const float* __restrict__ b1,
             const float* __restrict__ W2, const float* __restrict__ b2,
             float* __restrict__ dst)
{
    // LDS: Xs 4*32*CSTR (25600B) + Hb 4*16*HSTR (9216B) = 34816B
    __shared__ bf16_t smem[4 * 32 * CSTR + 4 * 16 * HSTR];

    const int tid  = threadIdx.x;
    const int wave = tid >> 6;
    const int lane = tid & 63;
    const int lrow = lane & 15;   // MFMA A-row / B-col / D-col
    const int g    = lane >> 4;   // 16-lane group

    bf16_t* Xw = smem + wave * 32 * CSTR;
    bf16_t* Hw = smem + 4 * 32 * CSTR + wave * 16 * HSTR;

    // ---- prologue: W1 frags via transient LDS stage (aliased into Xs area) ----
    for (int i = tid; i < 64 * 96; i += 256) {
        int o = i / 96, c = i - o * 96;
        smem[i] = (c < CX) ? (bf16_t)W1[o * CX + c] : (bf16_t)0.f;
    }
    __syncthreads();
    bf16x8 w1f[3][4];
    #pragma unroll
    for (int kc = 0; kc < 3; ++kc)
        #pragma unroll
        for (int rt = 0; rt < 4; ++rt)
            w1f[kc][rt] = *(const bf16x8*)&smem[(rt * 16 + lrow) * 96 + kc * 32 + g * 8];
    __syncthreads();
    // W2 frags
    for (int i = tid; i < 128 * 72; i += 256) {
        int o = i / 72, c = i - o * 72;
        smem[i] = (c < CMID) ? (bf16_t)W2[o * CMID + c] : (bf16_t)0.f;
    }
    __syncthreads();
    bf16x8 w2f[2][8];
    #pragma unroll
    for (int kc = 0; kc < 2; ++kc)
        #pragma unroll
        for (int ot = 0; ot < 8; ++ot)
            w2f[kc][ot] = *(const bf16x8*)&smem[(ot * 16 + lrow) * 72 + kc * 32 + g * 8];
    __syncthreads();
    // zero Xs region (pad chans 67..95 stay zero forever; 0..66 rewritten each iter)
    for (int i = tid; i < 4 * 32 * CSTR; i += 256) smem[i] = (bf16_t)0.f;
    __syncthreads();

    f32x4 b1f[4];
    #pragma unroll
    for (int rt = 0; rt < 4; ++rt) b1f[rt] = *(const f32x4*)(b1 + rt * 16 + g * 4);

    const size_t plane = (size_t)N_ * K_;
    const int cr = lane >> 3;            // channel-in-group 0..7
    const int k0 = (lane & 7) << 2;      // k base 0..28

    #pragma unroll 1
    for (int t = 0; t < TPG; ++t) {
        const int G = blockIdx.x * TPG + t;        // 0..8191
        const int b = G >> 11;
        const int n = ((G & 2047) << 2) + wave;

        // ---- stage X: one full 128B line per (c,n), register-staged ----
        {
            const size_t rbase = (size_t)n * K_ + k0;
            const float* dpb = dp + (size_t)b * 3  * plane + rbase;
            const float* fjb = fj + (size_t)b * 64 * plane + rbase;
            float4 v[9];
            #pragma unroll
            for (int j = 0; j < 9; ++j) {
                int c = j * 8 + cr;
                int cc = (c < CX) ? c : (CX - 1);
                const float* p = (cc < 3) ? dpb + (size_t)cc * plane
                                          : fjb + (size_t)(cc - 3) * plane;
                v[j] = *(const float4*)p;   // all issued before any LDS write
            }
            #pragma unroll
            for (int j = 0; j < 9; ++j) {
                int c = j * 8 + cr;
                if (c < CX) {
                    Xw[(k0 + 0) * CSTR + c] = (bf16_t)v[j].x;
                    Xw[(k0 + 1) * CSTR + c] = (bf16_t)v[j].y;
                    Xw[(k0 + 2) * CSTR + c] = (bf16_t)v[j].z;
                    Xw[(k0 + 3) * CSTR + c] = (bf16_t)v[j].w;
                }
            }
        }

        f32x4 macc[8];
        #pragma unroll
        for (int i = 0; i < 8; ++i) macc[i] = (f32x4){-3e30f, -3e30f, -3e30f, -3e30f};

        #pragma unroll
        for (int ct = 0; ct < 2; ++ct) {
            const int col = ct * 16 + lrow;
            // ---- layer 1: acc1 = W1 * X ----
            f32x4 acc1[4] = {};
            #pragma unroll
            for (int kc = 0; kc < 3; ++kc) {
                bf16x4 lo = *(const bf16x4*)&Xw[col * CSTR + kc * 32 + g * 8];
                bf16x4 hi = *(const bf16x4*)&Xw[col * CSTR + kc * 32 + g * 8 + 4];
                bf16x8 bf = __builtin_shufflevector(lo, hi, 0, 1, 2, 3, 4, 5, 6, 7);
                #pragma unroll
                for (int rt = 0; rt < 4; ++rt)
                    acc1[rt] = __builtin_amdgcn_mfma_f32_16x16x32_bf16(w1f[kc][rt], bf, acc1[rt], 0, 0, 0);
            }
            // ---- epilogue 1: bias+relu -> packed bf16 -> Hb (wave-private) ----
            #pragma unroll
            for (int rt = 0; rt < 4; ++rt) {
                float h0 = fmaxf(acc1[rt][0] + b1f[rt][0], 0.f);
                float h1 = fmaxf(acc1[rt][1] + b1f[rt][1], 0.f);
                float h2 = fmaxf(acc1[rt][2] + b1f[rt][2], 0.f);
                float h3 = fmaxf(acc1[rt][3] + b1f[rt][3], 0.f);
                *(uint2*)&Hw[lrow * HSTR + rt * 16 + g * 4] =
                    make_uint2(pack2bf(h0, h1), pack2bf(h2, h3));
            }
            // ---- layer 2: acc2 = W2 * H1 ----
            f32x4 acc2[8] = {};
            #pragma unroll
            for (int kc = 0; kc < 2; ++kc) {
                bf16x8 hb = *(const bf16x8*)&Hw[lrow * HSTR + kc * 32 + g * 8];
                #pragma unroll
                for (int ot = 0; ot < 8; ++ot)
                    acc2[ot] = __builtin_amdgcn_mfma_f32_16x16x32_bf16(w2f[kc][ot], hb, acc2[ot], 0, 0, 0);
            }
            // fold max over this 16-col half (bias deferred past the max)
            #pragma unroll
            for (int ot = 0; ot < 8; ++ot) {
                macc[ot][0] = fmaxf(macc[ot][0], acc2[ot][0]);
                macc[ot][1] = fmaxf(macc[ot][1], acc2[ot][1]);
                macc[ot][2] = fmaxf(macc[ot][2], acc2[ot][2]);
                macc[ot][3] = fmaxf(macc[ot][3], acc2[ot][3]);
            }
        }

        // ---- pool across the 16 col-lanes on the VALU pipe (DPP butterfly) ----
        #pragma unroll
        for (int ot = 0; ot < 8; ++ot) {
            macc[ot][0] = dpp_max16(macc[ot][0]);
            macc[ot][1] = dpp_max16(macc[ot][1]);
            macc[ot][2] = dpp_max16(macc[ot][2]);
            macc[ot][3] = dpp_max16(macc[ot][3]);
        }

        if (lrow == 0) {
            if (DIRECT) {
                float* op = dst + ((size_t)b * COUT) * N_ + n;
                #pragma unroll
                for (int ot = 0; ot < 8; ++ot) {
                    float4 bb = *(const float4*)(b2 + ot * 16 + g * 4);
                    op[(size_t)(ot * 16 + g * 4 + 0) * N_] = fmaxf(macc[ot][0] + bb.x, 0.f);
                    op[(size_t)(ot * 16 + g * 4 + 1) * N_] = fmaxf(macc[ot][1] + bb.y, 0.f);
                    op[(size_t)(ot * 16 + g * 4 + 2) * N_] = fmaxf(macc[ot][2] + bb.z, 0.f);
                    op[(size_t)(ot * 16 + g * 4 + 3) * N_] = fmaxf(macc[ot][3] + bb.w, 0.f);
                }
            } else {
                float* wp = dst + ((size_t)(b * N_ + n)) * COUT;  // ws[b][n][c]
                #pragma unroll
                for (int ot = 0; ot < 8; ++ot) {
                    float4 bb = *(const float4*)(b2 + ot * 16 + g * 4);
                    float4 o4;
                    o4.x = fmaxf(macc[ot][0] + bb.x, 0.f);
                    o4.y = fmaxf(macc[ot][1] + bb.y, 0.f);
                    o4.z = fmaxf(macc[ot][2] + bb.z, 0.f);
                    o4.w = fmaxf(macc[ot][3] + bb.w, 0.f);
                    *(float4*)(wp + ot * 16 + g * 4) = o4;
                }
            }
        }
    }
}

// ws[b][n][c] -> out[b][c][n], full lines on both sides
__global__ __launch_bounds__(256)
void sa_transpose(const float* __restrict__ ws, float* __restrict__ out)
{
    __shared__ float tile[32][136];
    const int t  = threadIdx.x;
    const int i  = blockIdx.x;         // 0..1023
    const int b  = i >> 8;
    const int n0 = (i & 255) << 5;

    const float* rp = ws + ((size_t)(b * N_ + n0)) * COUT;
    #pragma unroll
    for (int r = 0; r < 4; ++r) {
        int flat = (r * 256 + t) * 4;
        int nl = flat >> 7, c = flat & 127;
        float4 v = *(const float4*)(rp + (size_t)nl * COUT + c);
        *(float4*)&tile[nl][c] = v;
    }
    __syncthreads();
    float* op = out + (size_t)b * COUT * N_ + n0;
    const int nl4 = (t & 7) << 2;
    #pragma unroll
    for (int r2 = 0; r2 < 4; ++r2) {
        int c = r2 * 32 + (t >> 3);
        float4 o4;
        o4.x = tile[nl4 + 0][c];
        o4.y = tile[nl4 + 1][c];
        o4.z = tile[nl4 + 2][c];
        o4.w = tile[nl4 + 3][c];
        *(float4*)(op + (size_t)c * N_ + nl4) = o4;
    }
}

extern "C" void kernel_launch(void* const* d_in, const int* in_sizes, int n_in,
                              void* d_out, int out_size, void* d_ws, size_t ws_size,
                              hipStream_t stream) {
    // inputs: 0=p (unused), 1=f (unused), 2=dp, 3=fj, 4=W1, 5=b1, 6=W2, 7=b2
    const float* dp = (const float*)d_in[2];
    const float* fj = (const float*)d_in[3];
    const float* W1 = (const float*)d_in[4];
    const float* b1 = (const float*)d_in[5];
    const float* W2 = (const float*)d_in[6];
    const float* b2 = (const float*)d_in[7];
    float* out = (float*)d_out;

    const size_t ws_need = (size_t)B_ * N_ * COUT * sizeof(float);
    if (ws_size >= ws_need) {
        float* ws = (float*)d_ws;
        hipLaunchKernelGGL((sa_main<false>), dim3(2048), dim3(256), 0, stream,
                           dp, fj, W1, b1, W2, b2, ws);
        hipLaunchKernelGGL(sa_transpose, dim3(1024), dim3(256), 0, stream, ws, out);
    } else {
        hipLaunchKernelGGL((sa_main<true>), dim3(2048), dim3(256), 0, stream,
                           dp, fj, W1, b1, W2, b2, out);
    }
}

// Round 3
// 111.313 us; speedup vs baseline: 4.3524x; 1.5415x over previous
//
#include <hip/hip_runtime.h>
#include <hip/hip_bf16.h>
#include <stdint.h>

#define B_    4
#define N_    8192
#define K_    32
#define CX    67      // 3 + C_IN
#define CMID  64
#define COUT  128

#define CSTR  100     // Xs chan stride (>=96, NOT mult of 8: 4-way staging writes, b64 reads free)
#define HSTR  72      // Hbuf chan stride (mult of 8 for b128-aligned reads)
#define TPG   8       // n-groups per WG (each group = 4 n, one per wave)
#define NWG   1024

typedef __bf16 bf16_t;
typedef bf16_t bf16x8 __attribute__((ext_vector_type(8)));
typedef bf16_t bf16x4 __attribute__((ext_vector_type(4)));
typedef float  f32x4  __attribute__((ext_vector_type(4)));

__device__ __forceinline__ uint32_t pack2bf(float a, float b) {
    union { bf16_t h[2]; uint32_t u; } x;
    x.h[0] = (bf16_t)a; x.h[1] = (bf16_t)b;
    return x.u;
}

template<bool DIRECT>
__global__ __launch_bounds__(256, 2)
void sa_main(const float* __restrict__ dp, const float* __restrict__ fj,
             const float* __restrict__ W1, const float* __restrict__ b1,
             const float* __restrict__ W2, const float* __restrict__ b2,
             float* __restrict__ dst)
{
    // LDS: Xs 4*32*CSTR (25600B) + Hb 4*16*HSTR (9216B) = 34816B
    __shared__ bf16_t smem[4 * 32 * CSTR + 4 * 16 * HSTR];

    const int tid  = threadIdx.x;
    const int wave = tid >> 6;
    const int lane = tid & 63;
    const int lrow = lane & 15;   // MFMA row/col index within 16-tile
    const int g    = lane >> 4;   // 16-lane group

    bf16_t* Xw = smem + wave * 32 * CSTR;
    bf16_t* Hw = smem + 4 * 32 * CSTR + wave * 16 * HSTR;

    const size_t plane = (size_t)N_ * K_;
    const int cr = lane >> 3;            // staging: channel-in-group 0..7
    const int k0 = (lane & 7) << 2;      // staging: k base 0..28

    // ---- issue t=0 global loads first: latency hides under weight prologue ----
    float4 v[9];
    auto issue = [&](int Gi) {
        const int bb = Gi >> 11;
        const int nn = ((Gi & 2047) << 2) + wave;
        const size_t rbase = (size_t)nn * K_ + k0;
        const float* dpb = dp + (size_t)bb * 3  * plane + rbase;
        const float* fjb = fj + (size_t)bb * 64 * plane + rbase;
        #pragma unroll
        for (int j = 0; j < 9; ++j) {
            int c = j * 8 + cr;
            int cc = (c < CX) ? c : (CX - 1);
            const float* p = (cc < 3) ? dpb + (size_t)cc * plane
                                      : fjb + (size_t)(cc - 3) * plane;
            v[j] = *(const float4*)p;
        }
    };
    issue(blockIdx.x * TPG);

    // ---- prologue: W1 frags via transient LDS stage (aliased into Xs area) ----
    for (int i = tid; i < 64 * 96; i += 256) {
        int o = i / 96, c = i - o * 96;
        smem[i] = (c < CX) ? (bf16_t)W1[o * CX + c] : (bf16_t)0.f;
    }
    __syncthreads();
    bf16x8 w1f[3][4];
    #pragma unroll
    for (int kc = 0; kc < 3; ++kc)
        #pragma unroll
        for (int rt = 0; rt < 4; ++rt)
            w1f[kc][rt] = *(const bf16x8*)&smem[(rt * 16 + lrow) * 96 + kc * 32 + g * 8];
    __syncthreads();
    // W2 frags (same register contents as before; used as the B operand now)
    for (int i = tid; i < 128 * 72; i += 256) {
        int o = i / 72, c = i - o * 72;
        smem[i] = (c < CMID) ? (bf16_t)W2[o * CMID + c] : (bf16_t)0.f;
    }
    __syncthreads();
    bf16x8 w2f[2][8];
    #pragma unroll
    for (int kc = 0; kc < 2; ++kc)
        #pragma unroll
        for (int ot = 0; ot < 8; ++ot)
            w2f[kc][ot] = *(const bf16x8*)&smem[(ot * 16 + lrow) * 72 + kc * 32 + g * 8];
    __syncthreads();
    // zero Xs region (pad chans 67..95 stay zero forever; 0..66 rewritten each iter)
    for (int i = tid; i < 4 * 32 * CSTR; i += 256) smem[i] = (bf16_t)0.f;
    __syncthreads();

    f32x4 b1f[4];
    #pragma unroll
    for (int rt = 0; rt < 4; ++rt) b1f[rt] = *(const f32x4*)(b1 + rt * 16 + g * 4);
    float b2f[8];
    #pragma unroll
    for (int ot = 0; ot < 8; ++ot) b2f[ot] = b2[ot * 16 + lrow];

    #pragma unroll 1
    for (int t = 0; t < TPG; ++t) {
        const int G = blockIdx.x * TPG + t;        // 0..8191
        const int b = G >> 11;
        const int n = ((G & 2047) << 2) + wave;

        // ---- stage current v -> Xw (consumes v) ----
        #pragma unroll
        for (int j = 0; j < 9; ++j) {
            int c = j * 8 + cr;
            if (c < CX) {
                Xw[(k0 + 0) * CSTR + c] = (bf16_t)v[j].x;
                Xw[(k0 + 1) * CSTR + c] = (bf16_t)v[j].y;
                Xw[(k0 + 2) * CSTR + c] = (bf16_t)v[j].z;
                Xw[(k0 + 3) * CSTR + c] = (bf16_t)v[j].w;
            }
        }
        // ---- prefetch t+1 into the same regs: hides under MFMA+pool below ----
        {
            int Gn = G + 1;
            if (Gn > 8191) Gn = 8191;   // clamp: redundant load, values unused
            issue(Gn);
        }

        float macc[8];
        #pragma unroll
        for (int i = 0; i < 8; ++i) macc[i] = -3e38f;

        #pragma unroll
        for (int ct = 0; ct < 2; ++ct) {
            const int col = ct * 16 + lrow;
            // ---- layer 1: acc1 = W1 * X ----
            f32x4 acc1[4] = {};
            #pragma unroll
            for (int kc = 0; kc < 3; ++kc) {
                bf16x4 lo = *(const bf16x4*)&Xw[col * CSTR + kc * 32 + g * 8];
                bf16x4 hi = *(const bf16x4*)&Xw[col * CSTR + kc * 32 + g * 8 + 4];
                bf16x8 bfX = __builtin_shufflevector(lo, hi, 0, 1, 2, 3, 4, 5, 6, 7);
                #pragma unroll
                for (int rt = 0; rt < 4; ++rt)
                    acc1[rt] = __builtin_amdgcn_mfma_f32_16x16x32_bf16(w1f[kc][rt], bfX, acc1[rt], 0, 0, 0);
            }
            // ---- epilogue 1: bias+relu -> packed bf16 -> Hw (wave-private) ----
            #pragma unroll
            for (int rt = 0; rt < 4; ++rt) {
                float h0 = fmaxf(acc1[rt][0] + b1f[rt][0], 0.f);
                float h1 = fmaxf(acc1[rt][1] + b1f[rt][1], 0.f);
                float h2 = fmaxf(acc1[rt][2] + b1f[rt][2], 0.f);
                float h3 = fmaxf(acc1[rt][3] + b1f[rt][3], 0.f);
                *(uint2*)&Hw[lrow * HSTR + rt * 16 + g * 4] =
                    make_uint2(pack2bf(h0, h1), pack2bf(h2, h3));
            }
            // ---- layer 2 (operands swapped => D rows = k-positions) ----
            bf16x8 hb0 = *(const bf16x8*)&Hw[lrow * HSTR +  0 + g * 8];
            bf16x8 hb1 = *(const bf16x8*)&Hw[lrow * HSTR + 32 + g * 8];
            #pragma unroll
            for (int bt = 0; bt < 2; ++bt) {
                f32x4 a2[4] = {};
                #pragma unroll
                for (int o = 0; o < 4; ++o) {
                    a2[o] = __builtin_amdgcn_mfma_f32_16x16x32_bf16(hb0, w2f[0][bt * 4 + o], a2[o], 0, 0, 0);
                    a2[o] = __builtin_amdgcn_mfma_f32_16x16x32_bf16(hb1, w2f[1][bt * 4 + o], a2[o], 0, 0, 0);
                }
                // in-lane pool over 4 k-positions, fold into running max
                #pragma unroll
                for (int o = 0; o < 4; ++o) {
                    float m = fmaxf(fmaxf(a2[o][0], a2[o][1]), fmaxf(a2[o][2], a2[o][3]));
                    macc[bt * 4 + o] = fmaxf(macc[bt * 4 + o], m);
                }
            }
        }

        // ---- cross-group pool (xor16 + xor32), bias, relu ----
        #pragma unroll
        for (int ot = 0; ot < 8; ++ot) {
            float vv = macc[ot];
            vv = fmaxf(vv, __shfl_xor(vv, 16, 64));
            vv = fmaxf(vv, __shfl_xor(vv, 32, 64));
            macc[ot] = fmaxf(vv + b2f[ot], 0.f);
        }
        // group g stores ot = 2g, 2g+1 -> fully coalesced (all 64 lanes, 2 insts)
        float va = (g == 0) ? macc[0] : (g == 1) ? macc[2] : (g == 2) ? macc[4] : macc[6];
        float vb = (g == 0) ? macc[1] : (g == 1) ? macc[3] : (g == 2) ? macc[5] : macc[7];
        const int ca = g * 32 + lrow;
        const int cb = g * 32 + 16 + lrow;
        if (DIRECT) {
            float* op = dst + (size_t)b * COUT * N_ + n;
            op[(size_t)ca * N_] = va;
            op[(size_t)cb * N_] = vb;
        } else {
            float* wp = dst + ((size_t)(b * N_ + n)) * COUT;   // ws[b][n][c]
            wp[ca] = va;
            wp[cb] = vb;
        }
    }
}

// ws[b][n][c] -> out[b][c][n], full lines on both sides
__global__ __launch_bounds__(256)
void sa_transpose(const float* __restrict__ ws, float* __restrict__ out)
{
    __shared__ float tile[32][136];
    const int t  = threadIdx.x;
    const int i  = blockIdx.x;         // 0..1023
    const int b  = i >> 8;
    const int n0 = (i & 255) << 5;

    const float* rp = ws + ((size_t)(b * N_ + n0)) * COUT;
    #pragma unroll
    for (int r = 0; r < 4; ++r) {
        int flat = (r * 256 + t) * 4;
        int nl = flat >> 7, c = flat & 127;
        float4 v = *(const float4*)(rp + (size_t)nl * COUT + c);
        *(float4*)&tile[nl][c] = v;
    }
    __syncthreads();
    float* op = out + (size_t)b * COUT * N_ + n0;
    const int nl4 = (t & 7) << 2;
    #pragma unroll
    for (int r2 = 0; r2 < 4; ++r2) {
        int c = r2 * 32 + (t >> 3);
        float4 o4;
        o4.x = tile[nl4 + 0][c];
        o4.y = tile[nl4 + 1][c];
        o4.z = tile[nl4 + 2][c];
        o4.w = tile[nl4 + 3][c];
        *(float4*)(op + (size_t)c * N_ + nl4) = o4;
    }
}

extern "C" void kernel_launch(void* const* d_in, const int* in_sizes, int n_in,
                              void* d_out, int out_size, void* d_ws, size_t ws_size,
                              hipStream_t stream) {
    // inputs: 0=p (unused), 1=f (unused), 2=dp, 3=fj, 4=W1, 5=b1, 6=W2, 7=b2
    const float* dp = (const float*)d_in[2];
    const float* fj = (const float*)d_in[3];
    const float* W1 = (const float*)d_in[4];
    const float* b1 = (const float*)d_in[5];
    const float* W2 = (const float*)d_in[6];
    const float* b2 = (const float*)d_in[7];
    float* out = (float*)d_out;

    const size_t ws_need = (size_t)B_ * N_ * COUT * sizeof(float);
    if (ws_size >= ws_need) {
        float* ws = (float*)d_ws;
        hipLaunchKernelGGL((sa_main<false>), dim3(NWG), dim3(256), 0, stream,
                           dp, fj, W1, b1, W2, b2, ws);
        hipLaunchKernelGGL(sa_transpose, dim3(1024), dim3(256), 0, stream, ws, out);
    } else {
        hipLaunchKernelGGL((sa_main<true>), dim3(NWG), dim3(256), 0, stream,
                           dp, fj, W1, b1, W2, b2, out);
    }
}